// Round 4
// baseline (108015.649 us; speedup 1.0000x reference)
//
#include <hip/hip_runtime.h>
#include <hip/hip_bf16.h>
#include <cstdint>
#include <cstddef>

// ---------------------------------------------------------------------------
// FlumenHead: encoder MLP (32->512->512->1024) + 2048-step LSTM (D=9, F=1024)
// v4: wave-specialized persistent kernel, 32 WGs x 512 thr.
//  - 4 compute waves/WG (1 per SIMD): B-frags direct from LLC into pinned
//    B[32] regs (no LDS fill), A streamed from L2 with imm-offset loads,
//    264 MFMA/wave/step, lane-local cell update.
//  - 4 helper waves/WG: pack h -> bf16, contiguous 4KB sc1 publish in
//    consumer-fragment order hbuf[buf][kt=w][l4][b][e], vmcnt(0) ack, per-wave
//    tag store, h_seq writes. Publish-ack latency off the compute path.
//  - one __syncthreads per step; per-wave independent tag polling.
// ---------------------------------------------------------------------------

typedef __bf16 bf16x8_t __attribute__((ext_vector_type(8)));
typedef float f32x4_t __attribute__((ext_vector_type(4)));
typedef int   i32x4_t __attribute__((ext_vector_type(4)));
typedef unsigned long long u64_t;
typedef unsigned long long u64x2_t __attribute__((ext_vector_type(2)));
typedef unsigned short u16x4_t __attribute__((ext_vector_type(4)));

// workspace layout (bytes); total ~18.6 MB
#define WS_TAGS    0          // int  tags[2048][32][4] (16B per (t,w))   1 MB
#define WS_HBUF    1048576    // u16  hbuf[2][32 kt][4 l4][64 b][8] bf16 256 KB
#define WS_WSHUF   1310720    // u16  Wshuf[64 fb][32 kt][4 g][64 ln][8]   8 MB
#define WS_WAUG    9699328    // u16  Waug[4096][32] bf16               256 KB
#define WS_XHAT    9961472    // u16  Xhat[2048 t][64 b][32] bf16         8 MB
#define WS_H1      18350080   // f32  h1[64][512]                       128 KB
#define WS_H2      18481152   // f32  h2[64][512]                       128 KB

__device__ __forceinline__ unsigned short f2bf(float f) {
  unsigned int u = __float_as_uint(f);
  u = (u + 0x7fffu + ((u >> 16) & 1u)) >> 16;   // RNE
  return (unsigned short)u;
}
__device__ __forceinline__ float sigm(float x) { return 1.f / (1.f + __expf(-x)); }
__device__ __forceinline__ float tanh_f(float x) {
  float e = __expf(-2.f * fabsf(x));
  float r = (1.f - e) / (1.f + e);
  return copysignf(r, x);
}

// ---------------------------- encoder ----------------------------

__global__ void flumen_enc1(const float* __restrict__ x, const float* __restrict__ W,
                            const float* __restrict__ b, float* __restrict__ h1) {
  const int bb = blockIdx.x;   // batch 0..63
  const int o  = threadIdx.x;  // 0..511
  const f32x4_t* xr = (const f32x4_t*)(x + bb * 32);
  const f32x4_t* wr = (const f32x4_t*)(W + o * 32);
  float acc = b[o];
#pragma unroll
  for (int q = 0; q < 8; ++q) {
    f32x4_t xv = xr[q], wv = wr[q];
    acc += xv[0] * wv[0] + xv[1] * wv[1] + xv[2] * wv[2] + xv[3] * wv[3];
  }
  h1[bb * 512 + o] = fmaxf(acc, 0.f);
}

__global__ void flumen_enc2(const float* __restrict__ in, const float* __restrict__ W,
                            const float* __restrict__ bv, float* __restrict__ outb) {
  __shared__ float s[64 * 256];
  const int tid = threadIdx.x;
  const int ol = tid & 63, bg = tid >> 6;
  const int o = blockIdx.x * 64 + ol;
  float bias = bv[o];
  float acc[8];
#pragma unroll
  for (int q = 0; q < 8; ++q) acc[q] = bias;
  for (int p = 0; p < 2; ++p) {
    __syncthreads();
    for (int i = tid; i < 4096; i += 512) {
      int flat = i * 4;
      int bb = flat >> 8, kk = flat & 255;
      *(f32x4_t*)(s + flat) = *(const f32x4_t*)(in + bb * 512 + p * 256 + kk);
    }
    __syncthreads();
    for (int kk = 0; kk < 256; kk += 4) {
      f32x4_t wv = *(const f32x4_t*)(W + o * 512 + p * 256 + kk);
#pragma unroll
      for (int j = 0; j < 4; ++j) {
        float wj = wv[j];
#pragma unroll
        for (int q = 0; q < 8; ++q)
          acc[q] += wj * s[(bg * 8 + q) * 256 + kk + j];
      }
    }
  }
#pragma unroll
  for (int q = 0; q < 8; ++q)
    outb[(bg * 8 + q) * 512 + o] = fmaxf(acc[q], 0.f);
}

__global__ void flumen_enc3(const float* __restrict__ in, const float* __restrict__ W,
                            const float* __restrict__ bv, float* __restrict__ dout,
                            unsigned short* __restrict__ hbuf) {
  __shared__ float s[64 * 256];
  const int tid = threadIdx.x;
  const int ol = tid & 63, bg = tid >> 6;
  const int o = blockIdx.x * 64 + ol;   // 0..1023
  float bias = bv[o];
  float acc[8];
#pragma unroll
  for (int q = 0; q < 8; ++q) acc[q] = bias;
  for (int p = 0; p < 2; ++p) {
    __syncthreads();
    for (int i = tid; i < 4096; i += 512) {
      int flat = i * 4;
      int bb = flat >> 8, kk = flat & 255;
      *(f32x4_t*)(s + flat) = *(const f32x4_t*)(in + bb * 512 + p * 256 + kk);
    }
    __syncthreads();
    for (int kk = 0; kk < 256; kk += 4) {
      f32x4_t wv = *(const f32x4_t*)(W + o * 512 + p * 256 + kk);
#pragma unroll
      for (int j = 0; j < 4; ++j) {
        float wj = wv[j];
#pragma unroll
        for (int q = 0; q < 8; ++q)
          acc[q] += wj * s[(bg * 8 + q) * 256 + kk + j];
      }
    }
  }
  float* out_hseq = dout + 65536;
#pragma unroll
  for (int q = 0; q < 8; ++q) {
    int bb = bg * 8 + q;
    float v = acc[q];
    out_hseq[(size_t)bb * 2097152 + o] = v;   // h_seq[b][0][o]
    // hbuf[0][kt=o>>5][l4=(o>>3)&3][bb][e=o&7]
    hbuf[(o >> 5) * 2048 + ((o >> 3) & 3) * 512 + bb * 8 + (o & 7)] = f2bf(v);
  }
}

// ---------------------------- precompute ----------------------------

// W_hh -> fragment order Wshuf[fb][kt][g][lane][8]:
//  = W[(g*1024 + fb*16 + (lane&15))*1024 + kt*32 + (lane>>4)*8 + e]
__global__ void flumen_wshuf(const float* __restrict__ src, unsigned short* __restrict__ dst) {
  int idx = blockIdx.x * 512 + threadIdx.x;      // 0..524287
  int lane = idx & 63, g = (idx >> 6) & 3, kt = (idx >> 8) & 31, fb = idx >> 13;
  int r = g * 1024 + fb * 16 + (lane & 15);
  int k0 = kt * 32 + (lane >> 4) * 8;
  const float* sp = src + (size_t)r * 1024 + k0;
  f32x4_t v0 = *(const f32x4_t*)(sp);
  f32x4_t v1 = *(const f32x4_t*)(sp + 4);
  u16x4_t o0, o1;
#pragma unroll
  for (int j = 0; j < 4; ++j) { o0[j] = f2bf(v0[j]); o1[j] = f2bf(v1[j]); }
  u16x4_t* dp = (u16x4_t*)(dst + (size_t)idx * 8);
  dp[0] = o0; dp[1] = o1;
}

// Waug[r][0..8]=W_ih[r], [9]=bias[r], rest 0. grid=64.
__global__ void flumen_convaug(const float* __restrict__ wih, const float* __restrict__ bias,
                               unsigned short* __restrict__ dst) {
  int i = (blockIdx.x * 512 + threadIdx.x) * 4;
  int row = i >> 5, c0 = i & 31;
  u16x4_t o;
#pragma unroll
  for (int j = 0; j < 4; ++j) {
    int cc = c0 + j;
    float v = (cc < 9) ? wih[row * 9 + cc] : (cc == 9 ? bias[row] : 0.f);
    o[j] = f2bf(v);
  }
  *(u16x4_t*)(dst + i) = o;
}

// Xhat[t][b][0..8]=x[b][t][:], [9]=1.0, rest 0. grid=2048.
__global__ void flumen_convx(const float* __restrict__ xin, unsigned short* __restrict__ dst) {
  int i = (blockIdx.x * 512 + threadIdx.x) * 4;   // elem index, 4 at a time
  int b = i >> 16, t = (i >> 5) & 2047, c0 = i & 31;
  u16x4_t o;
#pragma unroll
  for (int j = 0; j < 4; ++j) {
    int cc = c0 + j;
    float v = (cc < 9) ? xin[((size_t)b * 2048 + t) * 9 + cc] : (cc == 9 ? 1.f : 0.f);
    o[j] = f2bf(v);
  }
  *(u16x4_t*)(dst + ((size_t)t * 64 + b) * 32 + c0) = o;
}

// ---------------------------- persistent LSTM ----------------------------
// 32 WGs x 512 thr, 1 WG/CU. WG w owns features [32w,32w+32), all 4 gates.
// Waves 0-3 (one per SIMD): compute. wave n: batches [16n,16n+16), both
// 16-feature halves, 4 gates -> acc[2][4], B[32] pinned from LLC.
// Waves 4-7: helpers. Pack/publish (contiguous 1KB sc1 per wave) + ack +
// tag + h_seq. One __syncthreads per step.
__global__ __launch_bounds__(512, 2) void flumen_lstm(
    const unsigned short* __restrict__ Wshuf,
    const unsigned short* __restrict__ Waug,
    const unsigned short* __restrict__ Xhat,
    unsigned short* hbuf, int* tags, float* out)
{
  __shared__ __align__(16) float hs[2][64][36];   // 18.4 KB staging

  float* out_hlast = out;
  float* out_hseq  = out + 65536;
  const int w    = blockIdx.x;       // 0..31
  const int tid  = threadIdx.x;
  const int lane = tid & 63;
  const int wave = tid >> 6;         // 0..7
  const int l15  = lane & 15;
  const int l4   = lane >> 4;

  if (wave < 4) {
    // ======================= compute wave (n = wave) =======================
    const int n = wave;
    const int batch = n * 16 + l15;
    const char* Ab0 = (const char*)Wshuf + (size_t)(w * 2) * 131072 + lane * 16;
    const char* Ab1 = Ab0 + 131072;

    // Waug frags (t-invariant): wfrag[hh][g]
    bf16x8_t wfrag[2][4];
#pragma unroll
    for (int hh = 0; hh < 2; ++hh)
#pragma unroll
      for (int g = 0; g < 4; ++g) {
        int row = g * 1024 + w * 32 + hh * 16 + l15;
        wfrag[hh][g] = *(const bf16x8_t*)(Waug + row * 32 + l4 * 8);
      }

    float carr[8] = {0.f, 0.f, 0.f, 0.f, 0.f, 0.f, 0.f, 0.f};

    for (int t = 0; t < 2048; ++t) {
      // x-term (independent of h_t): load + aug MFMAs hide under the poll
      bf16x8_t xf = *(const bf16x8_t*)(Xhat + ((size_t)t * 64 + batch) * 32 + l4 * 8);
      f32x4_t acc[2][4];
#pragma unroll
      for (int hh = 0; hh < 2; ++hh)
#pragma unroll
        for (int g = 0; g < 4; ++g)
          acc[hh][g] = __builtin_amdgcn_mfma_f32_16x16x32_bf16(
              wfrag[hh][g], xf, (f32x4_t){0.f, 0.f, 0.f, 0.f}, 0, 0, 0);

      if (t > 0) {
        if (lane < 32) {
          const char* tp = (const char*)tags + ((size_t)(t - 1) * 32 + lane) * 16;
          int iter = 0;
          while (true) {
            i32x4_t tv;
            asm volatile("global_load_dwordx4 %0, %1, off sc1\n\ts_waitcnt vmcnt(0)"
                         : "=v"(tv) : "v"(tp) : "memory");
            bool good = (tv[0] == t) && (tv[1] == t) && (tv[2] == t) && (tv[3] == t);
            if (__all(good) || ++iter >= (1 << 20)) break;
          }
        }
        __builtin_amdgcn_sched_barrier(0);
      }

      // B-frags: 32 contiguous 16B sc1 loads straight into pinned regs
      bf16x8_t B[32];
      const char* bp = (const char*)hbuf + (size_t)((t & 1) * 131072) + l4 * 1024 + batch * 16;
#pragma unroll
      for (int kt = 0; kt < 32; ++kt)
        asm volatile("global_load_dwordx4 %0, %1, off sc1"
                     : "=v"(B[kt]) : "v"(bp + (size_t)kt * 4096) : "memory");
      asm volatile("s_waitcnt vmcnt(0)" ::: "memory");
      __builtin_amdgcn_sched_barrier(0);

      // main K loop: A streamed from L2 (imm-offset folded), B from regs
#pragma unroll
      for (int kt = 0; kt < 32; ++kt) {
        const char* a0 = Ab0 + kt * 4096;
        const char* a1 = Ab1 + kt * 4096;
#pragma unroll
        for (int g = 0; g < 4; ++g)
          acc[0][g] = __builtin_amdgcn_mfma_f32_16x16x32_bf16(
              *(const bf16x8_t*)(a0 + g * 1024), B[kt], acc[0][g], 0, 0, 0);
#pragma unroll
        for (int g = 0; g < 4; ++g)
          acc[1][g] = __builtin_amdgcn_mfma_f32_16x16x32_bf16(
              *(const bf16x8_t*)(a1 + g * 1024), B[kt], acc[1][g], 0, 0, 0);
      }

      // lane-local cell update (8 cells: 2 hh x 4 j)
      f32x4_t hv0, hv1;
#pragma unroll
      for (int hh = 0; hh < 2; ++hh)
#pragma unroll
        for (int j = 0; j < 4; ++j) {
          float iv = acc[hh][0][j], fv = acc[hh][1][j];
          float gv = acc[hh][2][j], ov = acc[hh][3][j];
          float c = sigm(fv) * carr[hh * 4 + j] + sigm(iv) * tanh_f(gv);
          carr[hh * 4 + j] = c;
          float h = sigm(ov) * tanh_f(c);
          if (hh == 0) hv0[j] = h; else hv1[j] = h;
        }

      if (t < 2047) {
        *(f32x4_t*)&hs[t & 1][batch][l4 * 4]      = hv0;
        *(f32x4_t*)&hs[t & 1][batch][16 + l4 * 4] = hv1;
      } else {
        float* hl = out_hlast + batch * 1024 + w * 32 + l4 * 4;
        *(f32x4_t*)hl        = hv0;
        *(f32x4_t*)(hl + 16) = hv1;
      }
      __syncthreads();
    }
  } else {
    // ========================= helper wave =========================
    const int hw = wave - 4;   // 0..3 = l4p (publish 8-elem group)
    const int b  = lane;       // 0..63
    for (int t = 0; t < 2048; ++t) {
      __syncthreads();
      if (t >= 2047) continue;  // no h_{t+1} to publish at the last step
      // publish: pack hs -> bf16, contiguous 1KB per wave, sc1
      f32x4_t u0 = *(const f32x4_t*)&hs[t & 1][b][hw * 8];
      f32x4_t u1 = *(const f32x4_t*)&hs[t & 1][b][hw * 8 + 4];
      u64_t lo = (u64_t)f2bf(u0[0]) | ((u64_t)f2bf(u0[1]) << 16)
               | ((u64_t)f2bf(u0[2]) << 32) | ((u64_t)f2bf(u0[3]) << 48);
      u64_t hi = (u64_t)f2bf(u1[0]) | ((u64_t)f2bf(u1[1]) << 16)
               | ((u64_t)f2bf(u1[2]) << 32) | ((u64_t)f2bf(u1[3]) << 48);
      u64x2_t q = {lo, hi};
      char* dst = (char*)hbuf + (size_t)(((t + 1) & 1) * 131072)
                + w * 4096 + hw * 1024 + b * 16;
      asm volatile("global_store_dwordx4 %0, %1, off sc1" :: "v"(dst), "v"(q) : "memory");
      asm volatile("s_waitcnt vmcnt(0)" ::: "memory");
      if (lane == 0) {
        int* tp = tags + ((size_t)t * 32 + w) * 4 + hw;
        int val = t + 1;
        asm volatile("global_store_dword %0, %1, off sc1" :: "v"(tp), "v"(val) : "memory");
      }
      // h_seq[:, t+1, w*32..w*32+32): full-line f32 writes, off critical path
      int b2 = (hw * 64 + lane) >> 2, s = lane & 3;
      float* hd = out_hseq + ((size_t)b2 * 2048 + (size_t)(t + 1)) * 1024 + w * 32 + s * 8;
      *(f32x4_t*)hd       = *(const f32x4_t*)&hs[t & 1][b2][s * 8];
      *(f32x4_t*)(hd + 4) = *(const f32x4_t*)&hs[t & 1][b2][s * 8 + 4];
    }
  }
}

// ---------------------------- launch ----------------------------

extern "C" void kernel_launch(void* const* d_in, const int* in_sizes, int n_in,
                              void* d_out, int out_size, void* d_ws, size_t ws_size,
                              hipStream_t stream) {
  const float* initial_state = (const float*)d_in[0];
  const float* rnn_input     = (const float*)d_in[1];
  const float* enc_w0        = (const float*)d_in[2];
  const float* enc_b0        = (const float*)d_in[3];
  const float* enc_w1        = (const float*)d_in[4];
  const float* enc_b1        = (const float*)d_in[5];
  const float* enc_w2        = (const float*)d_in[6];
  const float* enc_b2        = (const float*)d_in[7];
  const float* w_ih          = (const float*)d_in[8];
  const float* w_hh          = (const float*)d_in[9];
  const float* bias          = (const float*)d_in[10];

  char* ws = (char*)d_ws;
  int*            tags  = (int*)(ws + WS_TAGS);
  unsigned short* hbuf  = (unsigned short*)(ws + WS_HBUF);
  unsigned short* Wshuf = (unsigned short*)(ws + WS_WSHUF);
  unsigned short* Waug  = (unsigned short*)(ws + WS_WAUG);
  unsigned short* Xhat  = (unsigned short*)(ws + WS_XHAT);
  float*          h1    = (float*)(ws + WS_H1);
  float*          h2    = (float*)(ws + WS_H2);
  float*          out   = (float*)d_out;

  hipMemsetAsync(tags, 0, 1048576, stream);
  flumen_enc1<<<64, 512, 0, stream>>>(initial_state, enc_w0, enc_b0, h1);
  flumen_enc2<<<8, 512, 0, stream>>>(h1, enc_w1, enc_b1, h2);
  flumen_enc3<<<16, 512, 0, stream>>>(h2, enc_w2, enc_b2, out, hbuf);
  flumen_wshuf<<<1024, 512, 0, stream>>>(w_hh, Wshuf);
  flumen_convaug<<<64, 512, 0, stream>>>(w_ih, bias, Waug);
  flumen_convx<<<2048, 512, 0, stream>>>(rnn_input, Xhat);
  flumen_lstm<<<32, 512, 0, stream>>>(Wshuf, Waug, Xhat, hbuf, tags, out);
}

// Round 5
// 19281.569 us; speedup vs baseline: 5.6020x; 5.6020x over previous
//
#include <hip/hip_runtime.h>
#include <hip/hip_bf16.h>
#include <cstdint>
#include <cstddef>

// ---------------------------------------------------------------------------
// FlumenHead: encoder MLP (32->512->512->1024) + 2048-step LSTM (D=9, F=1024)
// v5: A fully register-pinned (t-invariant, 128 VGPR), gate-interleaved
// M-tiles (row = 4*feat+gate) so the 16x16x32 C-layout makes the whole cell
// lane-local (acc[0..3] = i,f,g,o of one (batch,feature)). B via XOR-swizzled
// LDS (conflict-free at b128 floor, read addr = base ^ (kt<<6)). v2-style
// sync: per-wave tags, whole-wave blocking poll, 2 barriers/step.
// ---------------------------------------------------------------------------

typedef __bf16 bf16x8_t __attribute__((ext_vector_type(8)));
typedef float f32x4_t __attribute__((ext_vector_type(4)));
typedef int   i32x4_t __attribute__((ext_vector_type(4)));
typedef unsigned long long u64_t;
typedef unsigned long long u64x2_t __attribute__((ext_vector_type(2)));
typedef unsigned short u16x4_t __attribute__((ext_vector_type(4)));

// workspace layout (bytes); total ~18.6 MB
#define WS_TAGS    0          // int  tags[2048][32][4] (16B per (t,w))   1 MB
#define WS_HBUF    1048576    // u16  hbuf[2][32 w][64 b][32 f] bf16    256 KB
#define WS_WSHUF   1310720    // u16  Wshuf[256 mt][32 kt][64 ln][8]      8 MB
#define WS_WAUG    9699328    // u16  WaugI[256 mt][64 ln][8]           256 KB
#define WS_XHAT    9961472    // u16  Xhat[2048 t][64 b][32] bf16         8 MB
#define WS_H1      18350080   // f32  h1[64][512]                       128 KB
#define WS_H2      18481152   // f32  h2[64][512]                       128 KB

__device__ __forceinline__ unsigned short f2bf(float f) {
  unsigned int u = __float_as_uint(f);
  u = (u + 0x7fffu + ((u >> 16) & 1u)) >> 16;   // RNE
  return (unsigned short)u;
}
__device__ __forceinline__ float sigm(float x) { return 1.f / (1.f + __expf(-x)); }
__device__ __forceinline__ float tanh_f(float x) {
  float e = __expf(-2.f * fabsf(x));
  float r = (1.f - e) / (1.f + e);
  return copysignf(r, x);
}

// ---------------------------- encoder ----------------------------

__global__ void flumen_enc1(const float* __restrict__ x, const float* __restrict__ W,
                            const float* __restrict__ b, float* __restrict__ h1) {
  const int bb = blockIdx.x;   // batch 0..63
  const int o  = threadIdx.x;  // 0..511
  const f32x4_t* xr = (const f32x4_t*)(x + bb * 32);
  const f32x4_t* wr = (const f32x4_t*)(W + o * 32);
  float acc = b[o];
#pragma unroll
  for (int q = 0; q < 8; ++q) {
    f32x4_t xv = xr[q], wv = wr[q];
    acc += xv[0] * wv[0] + xv[1] * wv[1] + xv[2] * wv[2] + xv[3] * wv[3];
  }
  h1[bb * 512 + o] = fmaxf(acc, 0.f);
}

__global__ void flumen_enc2(const float* __restrict__ in, const float* __restrict__ W,
                            const float* __restrict__ bv, float* __restrict__ outb) {
  __shared__ float s[64 * 256];
  const int tid = threadIdx.x;
  const int ol = tid & 63, bg = tid >> 6;
  const int o = blockIdx.x * 64 + ol;
  float bias = bv[o];
  float acc[8];
#pragma unroll
  for (int q = 0; q < 8; ++q) acc[q] = bias;
  for (int p = 0; p < 2; ++p) {
    __syncthreads();
    for (int i = tid; i < 4096; i += 512) {
      int flat = i * 4;
      int bb = flat >> 8, kk = flat & 255;
      *(f32x4_t*)(s + flat) = *(const f32x4_t*)(in + bb * 512 + p * 256 + kk);
    }
    __syncthreads();
    for (int kk = 0; kk < 256; kk += 4) {
      f32x4_t wv = *(const f32x4_t*)(W + o * 512 + p * 256 + kk);
#pragma unroll
      for (int j = 0; j < 4; ++j) {
        float wj = wv[j];
#pragma unroll
        for (int q = 0; q < 8; ++q)
          acc[q] += wj * s[(bg * 8 + q) * 256 + kk + j];
      }
    }
  }
#pragma unroll
  for (int q = 0; q < 8; ++q)
    outb[(bg * 8 + q) * 512 + o] = fmaxf(acc[q], 0.f);
}

__global__ void flumen_enc3(const float* __restrict__ in, const float* __restrict__ W,
                            const float* __restrict__ bv, float* __restrict__ dout,
                            unsigned short* __restrict__ hbuf) {
  __shared__ float s[64 * 256];
  const int tid = threadIdx.x;
  const int ol = tid & 63, bg = tid >> 6;
  const int o = blockIdx.x * 64 + ol;   // 0..1023
  float bias = bv[o];
  float acc[8];
#pragma unroll
  for (int q = 0; q < 8; ++q) acc[q] = bias;
  for (int p = 0; p < 2; ++p) {
    __syncthreads();
    for (int i = tid; i < 4096; i += 512) {
      int flat = i * 4;
      int bb = flat >> 8, kk = flat & 255;
      *(f32x4_t*)(s + flat) = *(const f32x4_t*)(in + bb * 512 + p * 256 + kk);
    }
    __syncthreads();
    for (int kk = 0; kk < 256; kk += 4) {
      f32x4_t wv = *(const f32x4_t*)(W + o * 512 + p * 256 + kk);
#pragma unroll
      for (int j = 0; j < 4; ++j) {
        float wj = wv[j];
#pragma unroll
        for (int q = 0; q < 8; ++q)
          acc[q] += wj * s[(bg * 8 + q) * 256 + kk + j];
      }
    }
  }
  float* out_hseq = dout + 65536;
#pragma unroll
  for (int q = 0; q < 8; ++q) {
    int bb = bg * 8 + q;
    float v = acc[q];
    out_hseq[(size_t)bb * 2097152 + o] = v;            // h_seq[b][0][o]
    hbuf[(o >> 5) * 2048 + bb * 32 + (o & 31)] = f2bf(v);  // hbuf[0][w'][b][f]
  }
}

// ---------------------------- precompute ----------------------------

// Gate-interleaved A fragments: Wshuf[mt][kt][lane][8],
// A row r = lane&15 -> gate g = r&3, feature f = mt*4 + (r>>2);
// k = kt*32 + (lane>>4)*8 + e; src = w_hh[(g*1024+f)*1024 + k].
__global__ void flumen_wshuf(const float* __restrict__ src, unsigned short* __restrict__ dst) {
  int idx = blockIdx.x * 512 + threadIdx.x;      // 0..524287
  int lane = idx & 63, kt = (idx >> 6) & 31, mt = idx >> 11;
  int r = lane & 15;
  int g = r & 3, f = mt * 4 + (r >> 2);
  int k0 = kt * 32 + (lane >> 4) * 8;
  const float* sp = src + (size_t)(g * 1024 + f) * 1024 + k0;
  f32x4_t v0 = *(const f32x4_t*)(sp);
  f32x4_t v1 = *(const f32x4_t*)(sp + 4);
  u16x4_t o0, o1;
#pragma unroll
  for (int j = 0; j < 4; ++j) { o0[j] = f2bf(v0[j]); o1[j] = f2bf(v1[j]); }
  u16x4_t* dp = (u16x4_t*)(dst + (size_t)idx * 8);
  dp[0] = o0; dp[1] = o1;
}

// Gate-interleaved augmented fragments: WaugI[mt][lane][8], K=32:
// k<9 -> w_ih[(g*1024+f)*9+k], k==9 -> bias[g*1024+f], else 0.
__global__ void flumen_waugi(const float* __restrict__ wih, const float* __restrict__ bias,
                             unsigned short* __restrict__ dst) {
  int idx = blockIdx.x * 512 + threadIdx.x;      // 0..16383
  int lane = idx & 63, mt = idx >> 6;
  int r = lane & 15;
  int g = r & 3, f = mt * 4 + (r >> 2);
  int k0 = (lane >> 4) * 8;
  unsigned short o[8];
#pragma unroll
  for (int j = 0; j < 8; ++j) {
    int k = k0 + j;
    float v = (k < 9) ? wih[(size_t)(g * 1024 + f) * 9 + k]
                      : (k == 9 ? bias[g * 1024 + f] : 0.f);
    o[j] = f2bf(v);
  }
  u16x4_t* dp = (u16x4_t*)(dst + (size_t)idx * 8);
  dp[0] = *(u16x4_t*)&o[0];
  dp[1] = *(u16x4_t*)&o[4];
}

// Xhat[t][b][0..8]=x[b][t][:], [9]=1.0, rest 0. grid=2048.
__global__ void flumen_convx(const float* __restrict__ xin, unsigned short* __restrict__ dst) {
  int i = (blockIdx.x * 512 + threadIdx.x) * 4;   // elem index, 4 at a time
  int b = i >> 16, t = (i >> 5) & 2047, c0 = i & 31;
  u16x4_t o;
#pragma unroll
  for (int j = 0; j < 4; ++j) {
    int cc = c0 + j;
    float v = (cc < 9) ? xin[((size_t)b * 2048 + t) * 9 + cc] : (cc == 9 ? 1.f : 0.f);
    o[j] = f2bf(v);
  }
  *(u16x4_t*)(dst + ((size_t)t * 64 + b) * 32 + c0) = o;
}

// ---------------------------- persistent LSTM ----------------------------
// 32 WGs x 512 thr, 1 WG/CU (137 KB LDS). WG w owns features [32w,32w+32).
// Wave m (0..7) owns M-tile mt = w*8+m: rows = 4 feats x 4 gates interleaved.
// A pinned in 128 VGPRs. B from swizzled LDS: chunk (b, o16) stored at
// b*2048 + ((o16 ^ (b&7))<<4); K-loop read addr = Bbase ^ (kt<<6).
// Cell fully lane-local: acc[0..3] = i,f,g,o of (batch = n*16+l15,
// feature = w*32 + m*4 + l4).
__global__ __launch_bounds__(512, 1) void flumen_lstm(
    const unsigned short* __restrict__ Wshuf,
    const unsigned short* __restrict__ WaugI,
    const unsigned short* __restrict__ Xhat,
    unsigned short* hbuf, int* tags, float* out)
{
  __shared__ __align__(16) char smem[140544];
  char*  h_lds = smem;                           // 128KB swizzled B image
  float* hs    = (float*)(smem + 131072);        // [64][36] f32 staging

  float* out_hlast = out;
  float* out_hseq  = out + 65536;
  const int w    = blockIdx.x;       // 0..31
  const int tid  = threadIdx.x;
  const int lane = tid & 63;
  const int m    = tid >> 6;         // wave = M-tile index 0..7
  const int l15  = lane & 15;
  const int l4   = lane >> 4;
  const int s    = l15 & 7;          // = b&7 for all n (n*16 ≡ 0 mod 8)
  // B read base (n=0): addr(kt,n) = (Bbase0 + n*32768) ^ (kt<<6)
  const int Bbase0 = l15 * 2048 + ((l4 ^ (s & 3)) << 4) + ((s >> 2) << 6);

  // pinned A: 32 K-step fragments, t-invariant, 128 VGPRs
  bf16x8_t Apin[32];
  {
    const char* ap = (const char*)Wshuf + ((size_t)(w * 8 + m) * 32) * 1024 + lane * 16;
#pragma unroll
    for (int kt = 0; kt < 32; ++kt)
      Apin[kt] = *(const bf16x8_t*)(ap + kt * 1024);
  }
  const bf16x8_t wfragI =
      *(const bf16x8_t*)((const char*)WaugI + (size_t)(w * 8 + m) * 1024 + lane * 16);

  // fill: t-invariant swizzled LDS write addresses (16 chunks/thread)
  int lds_addr[16];
#pragma unroll
  for (int i = 0; i < 16; ++i) {
    int goff = i * 8192 + tid * 16;
    int b = (goff >> 6) & 63;
    int o16 = ((goff >> 12) << 2) | ((goff >> 4) & 3);
    lds_addr[i] = b * 2048 + ((o16 ^ (b & 7)) << 4);
  }

  float carr[4] = {0.f, 0.f, 0.f, 0.f};

  for (int t = 0; t < 2048; ++t) {
    // x fragments (independent of h_t) — prefetch before the poll
    bf16x8_t xf[4];
#pragma unroll
    for (int n = 0; n < 4; ++n)
      xf[n] = *(const bf16x8_t*)(Xhat + ((size_t)t * 64 + n * 16 + l15) * 32 + l4 * 8);

    if (t > 0) {
      if (lane < 32) {   // whole wave blocks (divergent branch = exec mask)
        const char* tp = (const char*)tags + ((size_t)(t - 1) * 32 + lane) * 16;
        int iter = 0;
        while (true) {
          i32x4_t tv;
          asm volatile("global_load_dwordx4 %0, %1, off sc1\n\ts_waitcnt vmcnt(0)"
                       : "=v"(tv) : "v"(tp) : "memory");
          bool good = (tv[0] == t) && (tv[1] == t) && (tv[2] == t) && (tv[3] == t);
          if (__all(good) || ++iter >= (1 << 20)) break;
        }
      }
      __builtin_amdgcn_sched_barrier(0);
    }

    // cooperative fill: hbuf[t&1] -> swizzled LDS, 2 rounds of 8 chunks
    {
      const char* src0 = (const char*)hbuf + (size_t)((t & 1) * 131072) + tid * 16;
      f32x4_t v[8];
#pragma unroll
      for (int i = 0; i < 8; ++i)
        asm volatile("global_load_dwordx4 %0, %1, off sc1"
                     : "=v"(v[i]) : "v"(src0 + i * 8192) : "memory");
      asm volatile("s_waitcnt vmcnt(0)" ::: "memory");
      __builtin_amdgcn_sched_barrier(0);
#pragma unroll
      for (int i = 0; i < 8; ++i)
        *(f32x4_t*)(h_lds + lds_addr[i]) = v[i];
#pragma unroll
      for (int i = 0; i < 8; ++i)
        asm volatile("global_load_dwordx4 %0, %1, off sc1"
                     : "=v"(v[i]) : "v"(src0 + (i + 8) * 8192) : "memory");
      asm volatile("s_waitcnt vmcnt(0)" ::: "memory");
      __builtin_amdgcn_sched_barrier(0);
#pragma unroll
      for (int i = 0; i < 8; ++i)
        *(f32x4_t*)(h_lds + lds_addr[i + 8]) = v[i];
    }
    __syncthreads();

    // K loop per batch-tile: A from pinned regs, B from swizzled LDS
#pragma unroll
    for (int n = 0; n < 4; ++n) {
      f32x4_t acc = __builtin_amdgcn_mfma_f32_16x16x32_bf16(
          wfragI, xf[n], (f32x4_t){0.f, 0.f, 0.f, 0.f}, 0, 0, 0);
      const int bb = Bbase0 + n * 32768;
#pragma unroll
      for (int kt = 0; kt < 32; ++kt) {
        bf16x8_t bf = *(const bf16x8_t*)(h_lds + (bb ^ (kt << 6)));
        acc = __builtin_amdgcn_mfma_f32_16x16x32_bf16(Apin[kt], bf, acc, 0, 0, 0);
      }
      // lane-local cell: acc = {i,f,g,o} of (batch n*16+l15, feat m*4+l4)
      float c = sigm(acc[1]) * carr[n] + sigm(acc[0]) * tanh_f(acc[2]);
      carr[n] = c;
      float h = sigm(acc[3]) * tanh_f(c);
      if (t < 2047) {
        hs[(n * 16 + l15) * 36 + m * 4 + l4] = h;
      } else {
        out_hlast[(n * 16 + l15) * 1024 + w * 32 + m * 4 + l4] = h;
      }
    }

    if (t < 2047) {
      __syncthreads();
      if (m < 4) {
        // publish: pack to bf16, contiguous 1KB/wave in consumer layout, sc1
        int b = m * 16 + (lane >> 2), fq = lane & 3;
        f32x4_t u0 = *(const f32x4_t*)(hs + b * 36 + fq * 8);
        f32x4_t u1 = *(const f32x4_t*)(hs + b * 36 + fq * 8 + 4);
        u64_t lo = (u64_t)f2bf(u0[0]) | ((u64_t)f2bf(u0[1]) << 16)
                 | ((u64_t)f2bf(u0[2]) << 32) | ((u64_t)f2bf(u0[3]) << 48);
        u64_t hi = (u64_t)f2bf(u1[0]) | ((u64_t)f2bf(u1[1]) << 16)
                 | ((u64_t)f2bf(u1[2]) << 32) | ((u64_t)f2bf(u1[3]) << 48);
        u64x2_t q = {lo, hi};
        char* dst = (char*)hbuf + (size_t)(((t + 1) & 1) * 131072)
                  + w * 4096 + b * 64 + fq * 16;
        asm volatile("global_store_dwordx4 %0, %1, off sc1" :: "v"(dst), "v"(q) : "memory");
        asm volatile("s_waitcnt vmcnt(0)" ::: "memory");
        if (lane == 0) {
          int* tp = tags + ((size_t)t * 32 + w) * 4 + m;
          int val = t + 1;
          asm volatile("global_store_dword %0, %1, off sc1" :: "v"(tp), "v"(val) : "memory");
        }
      } else {
        // h_seq[:, t+1, w*32..+32): full-line f32 writes, off critical path
        int b = (m - 4) * 16 + (lane >> 2), sg = lane & 3;
        float* hd = out_hseq + ((size_t)b * 2048 + (size_t)(t + 1)) * 1024 + w * 32 + sg * 8;
        *(f32x4_t*)hd       = *(const f32x4_t*)(hs + b * 36 + sg * 8);
        *(f32x4_t*)(hd + 4) = *(const f32x4_t*)(hs + b * 36 + sg * 8 + 4);
      }
    }
  }
}

// ---------------------------- launch ----------------------------

extern "C" void kernel_launch(void* const* d_in, const int* in_sizes, int n_in,
                              void* d_out, int out_size, void* d_ws, size_t ws_size,
                              hipStream_t stream) {
  const float* initial_state = (const float*)d_in[0];
  const float* rnn_input     = (const float*)d_in[1];
  const float* enc_w0        = (const float*)d_in[2];
  const float* enc_b0        = (const float*)d_in[3];
  const float* enc_w1        = (const float*)d_in[4];
  const float* enc_b1        = (const float*)d_in[5];
  const float* enc_w2        = (const float*)d_in[6];
  const float* enc_b2        = (const float*)d_in[7];
  const float* w_ih          = (const float*)d_in[8];
  const float* w_hh          = (const float*)d_in[9];
  const float* bias          = (const float*)d_in[10];

  char* ws = (char*)d_ws;
  int*            tags  = (int*)(ws + WS_TAGS);
  unsigned short* hbuf  = (unsigned short*)(ws + WS_HBUF);
  unsigned short* Wshuf = (unsigned short*)(ws + WS_WSHUF);
  unsigned short* WaugI = (unsigned short*)(ws + WS_WAUG);
  unsigned short* Xhat  = (unsigned short*)(ws + WS_XHAT);
  float*          h1    = (float*)(ws + WS_H1);
  float*          h2    = (float*)(ws + WS_H2);
  float*          out   = (float*)d_out;

  hipMemsetAsync(tags, 0, 1048576, stream);
  flumen_enc1<<<64, 512, 0, stream>>>(initial_state, enc_w0, enc_b0, h1);
  flumen_enc2<<<8, 512, 0, stream>>>(h1, enc_w1, enc_b1, h2);
  flumen_enc3<<<16, 512, 0, stream>>>(h2, enc_w2, enc_b2, out, hbuf);
  flumen_wshuf<<<1024, 512, 0, stream>>>(w_hh, Wshuf);
  flumen_waugi<<<32, 512, 0, stream>>>(w_ih, bias, WaugI);
  flumen_convx<<<2048, 512, 0, stream>>>(rnn_input, Xhat);
  flumen_lstm<<<32, 512, 0, stream>>>(Wshuf, WaugI, Xhat, hbuf, tags, out);
}